// Round 9
// baseline (305.724 us; speedup 1.0000x reference)
//
#include <hip/hip_runtime.h>
#include <hip/hip_fp16.h>

#define N_NODES  20000
#define N_EDGES  320000
#define N_GRAPHS 128

typedef _Float16 half8 __attribute__((ext_vector_type(8)));
typedef float    f32x4 __attribute__((ext_vector_type(4)));

__global__ void fill_zero(float* __restrict__ p, int n) {
    int i = blockIdx.x * blockDim.x + threadIdx.x;
    int stride = gridDim.x * blockDim.x;
    for (; i < n; i += stride) p[i] = 0.f;
}

// ---------- f32 -> fp16 convert (4 elems/thread) ----------
__global__ void f32_to_h(const float* __restrict__ in, __half* __restrict__ o, int n4) {
    int i = blockIdx.x * blockDim.x + threadIdx.x;
    if (i >= n4) return;
    float4 v = *reinterpret_cast<const float4*>(&in[i * 4]);
    union { __half2 h2[2]; uint2 u; } pk;
    pk.h2[0] = __floats2half2_rn(v.x, v.y);
    pk.h2[1] = __floats2half2_rn(v.z, v.w);
    *reinterpret_cast<uint2*>(&o[i * 4]) = pk.u;
}

// ---------- W[R,C] f32 -> WT[C,R] fp16 ----------
__global__ void transpose_h(const float* __restrict__ W, __half* __restrict__ WT,
                            int R, int C) {
    int i = blockIdx.x * blockDim.x + threadIdx.x;
    if (i >= R * C) return;
    int r = i / C, c = i - r * C;
    WT[(size_t)c * R + r] = __float2half(W[i]);
}

// ---------- MFMA fp16 GEMM + fused el/er ----------
template <int BM, int BN, int WM, int WN, int H, int D>
__global__ __launch_bounds__(256) void gemm_mfma(
        const __half* __restrict__ A, const __half* __restrict__ BT,
        __half* __restrict__ C, const float* __restrict__ al,
        const float* __restrict__ ar, float* __restrict__ el,
        float* __restrict__ er, int Mm, int Nn, int Kk) {
    constexpr int BK  = 32;
    constexpr int MFR = WM / 16, NFR = WN / 16;
    constexpr int WCOLS = BN / WN;
    __shared__ __align__(16) __half As[BM * BK];
    __shared__ __align__(16) __half Bs[BN * BK];
    const int tid  = threadIdx.x;
    const int w    = tid >> 6, lane = tid & 63;
    const int wr   = w / WCOLS, wc = w % WCOLS;
    const int brow = blockIdx.x * BM;
    const int bcol = blockIdx.y * BN;
    const int lr   = lane & 15;
    const int lk   = (lane >> 4) * 8;

    f32x4 acc[MFR][NFR] = {};

    for (int k0 = 0; k0 < Kk; k0 += BK) {
        for (int c = tid; c < BM * 4; c += 256) {
            int r = c >> 2, ko = (c & 3) * 8;
            int gr = brow + r; if (gr >= Mm) gr = Mm - 1;
            int off = (r * BK + ko) ^ ((r & 7) << 3);
            *reinterpret_cast<uint4*>(&As[off]) =
                *reinterpret_cast<const uint4*>(&A[(size_t)gr * Kk + k0 + ko]);
        }
        for (int c = tid; c < BN * 4; c += 256) {
            int r = c >> 2, ko = (c & 3) * 8;
            int off = (r * BK + ko) ^ ((r & 7) << 3);
            *reinterpret_cast<uint4*>(&Bs[off]) =
                *reinterpret_cast<const uint4*>(&BT[(size_t)(bcol + r) * Kk + k0 + ko]);
        }
        __syncthreads();
        half8 af[MFR], bf[NFR];
#pragma unroll
        for (int m = 0; m < MFR; ++m) {
            int r = wr * WM + m * 16 + lr;
            af[m] = *reinterpret_cast<const half8*>(&As[(r * BK + lk) ^ ((r & 7) << 3)]);
        }
#pragma unroll
        for (int n = 0; n < NFR; ++n) {
            int r = wc * WN + n * 16 + lr;
            bf[n] = *reinterpret_cast<const half8*>(&Bs[(r * BK + lk) ^ ((r & 7) << 3)]);
        }
#pragma unroll
        for (int m = 0; m < MFR; ++m)
#pragma unroll
            for (int n = 0; n < NFR; ++n)
                acc[m][n] = __builtin_amdgcn_mfma_f32_16x16x32_f16(af[m], bf[n], acc[m][n], 0, 0, 0);
        __syncthreads();
    }

#pragma unroll
    for (int m = 0; m < MFR; ++m) {
        int r0 = brow + wr * WM + m * 16 + ((lane >> 4) << 2);
#pragma unroll
        for (int n = 0; n < NFR; ++n) {
            int cc = bcol + wc * WN + n * 16 + lr;
#pragma unroll
            for (int g = 0; g < 4; ++g)
                if (r0 + g < Mm) C[(size_t)(r0 + g) * Nn + cc] = __float2half(acc[m][n][g]);
        }
    }
    const int h = (bcol + wc * WN) / D;
    float alv[NFR], arv[NFR];
#pragma unroll
    for (int n = 0; n < NFR; ++n) {
        alv[n] = al[bcol + wc * WN + n * 16 + lr];
        arv[n] = ar[bcol + wc * WN + n * 16 + lr];
    }
#pragma unroll
    for (int m = 0; m < MFR; ++m) {
#pragma unroll
        for (int g = 0; g < 4; ++g) {
            float pl = 0.f, pr = 0.f;
#pragma unroll
            for (int n = 0; n < NFR; ++n) {
                pl += acc[m][n][g] * alv[n];
                pr += acc[m][n][g] * arv[n];
            }
            pl += __shfl_xor(pl, 1); pl += __shfl_xor(pl, 2);
            pl += __shfl_xor(pl, 4); pl += __shfl_xor(pl, 8);
            pr += __shfl_xor(pr, 1); pr += __shfl_xor(pr, 2);
            pr += __shfl_xor(pr, 4); pr += __shfl_xor(pr, 8);
            int gr = brow + wr * WM + m * 16 + ((lane >> 4) << 2) + g;
            if (lr == 0 && gr < Mm) {
                if constexpr (WN == D) {
                    el[(size_t)gr * H + h] = pl;
                    er[(size_t)gr * H + h] = pr;
                } else {
                    atomicAdd(&el[(size_t)gr * H + h], pl);
                    atomicAdd(&er[(size_t)gr * H + h], pr);
                }
            }
        }
    }
}

// ---------- CSR build: histogram -> scan -> scatter ----------
__global__ void hist_kernel(const int* __restrict__ dst, int* __restrict__ deg, int E) {
    int e = blockIdx.x * blockDim.x + threadIdx.x;
    if (e >= E) return;
    atomicAdd(&deg[dst[e]], 1);
}

__global__ void scan_kernel(const int* __restrict__ deg, int* __restrict__ rowptr, int n) {
    __shared__ int partial[1024];
    const int t = threadIdx.x;
    const int CH = (n + 1023) / 1024;
    const int base = t * CH;
    int local = 0;
    for (int i = 0; i < CH; ++i)
        if (base + i < n) local += deg[base + i];
    partial[t] = local;
    __syncthreads();
    for (int o = 1; o < 1024; o <<= 1) {
        int v = (t >= o) ? partial[t - o] : 0;
        __syncthreads();
        partial[t] += v;
        __syncthreads();
    }
    int run = (t == 0) ? 0 : partial[t - 1];
    for (int i = 0; i < CH; ++i) {
        if (base + i <= n) rowptr[base + i] = run;
        if (base + i < n) run += deg[base + i];
    }
}

__global__ void scatter_kernel(const int* __restrict__ src, const int* __restrict__ dst,
                               const int* __restrict__ rowptr, int* __restrict__ cursor,
                               int* __restrict__ esrc, int* __restrict__ edst, int E) {
    int e = blockIdx.x * blockDim.x + threadIdx.x;
    if (e >= E) return;
    int d = dst[e];
    int pos = rowptr[d] + atomicAdd(&cursor[d], 1);
    esrc[pos] = src[e];
    edst[pos] = d;
}

// ---------- edge-weight precompute (removes 16x-redundant exp from aggr) ---
// w[h][pos] = exp(lrelu(el[src,h] + er[dst,h])), CSR-position indexed.
__global__ void edge_w8(const float* __restrict__ el, const float* __restrict__ er,
                        const int* __restrict__ esrc, const int* __restrict__ edst,
                        float* __restrict__ w, int E) {
    int p = blockIdx.x * blockDim.x + threadIdx.x;
    if (p >= E) return;
    int s = esrc[p], d = edst[p];
    float4 l0 = *reinterpret_cast<const float4*>(&el[s * 8]);
    float4 l1 = *reinterpret_cast<const float4*>(&el[s * 8 + 4]);
    float4 r0 = *reinterpret_cast<const float4*>(&er[d * 8]);
    float4 r1 = *reinterpret_cast<const float4*>(&er[d * 8 + 4]);
    float xs[8] = {l0.x + r0.x, l0.y + r0.y, l0.z + r0.z, l0.w + r0.w,
                   l1.x + r1.x, l1.y + r1.y, l1.z + r1.z, l1.w + r1.w};
#pragma unroll
    for (int h = 0; h < 8; ++h) {
        float x = xs[h];
        x = (x > 0.f) ? x : 0.2f * x;
        w[(size_t)h * E + p] = __expf(x);
    }
}

__global__ void edge_w1(const float* __restrict__ el, const float* __restrict__ er,
                        const int* __restrict__ esrc, const int* __restrict__ edst,
                        float* __restrict__ w, int E) {
    int p = blockIdx.x * blockDim.x + threadIdx.x;
    if (p >= E) return;
    float x = el[esrc[p]] + er[edst[p]];
    x = (x > 0.f) ? x : 0.2f * x;
    w[p] = __expf(x);
}

// ---------- per-node GAT aggregation: precomputed weights + nt stores ------
// blockIdx&7 -> column slice (XCD affinity). Output streams bypass L2 via
// nontemporal stores so the feat slice can stay L2-resident.
template <int H, int D, int CPS, bool HOUT>
__global__ void node_aggr_w(const __half* __restrict__ feat, const float* __restrict__ wbuf,
                            const int* __restrict__ rowptr, const int* __restrict__ esrc,
                            const float* __restrict__ bias, void* __restrict__ rst_,
                            int N, int E) {
    constexpr int F   = H * D;
    constexpr int TPN = CPS / 4;
    constexpr int NPB = 256 / TPN;
    const int slice  = blockIdx.x & 7;
    const int nchunk = blockIdx.x >> 3;
    const int tid = threadIdx.x;
    const int n  = nchunk * NPB + tid / TPN;
    if (n >= N) return;
    const int col = (slice * TPN + (tid % TPN)) * 4;
    const float* ws = wbuf + ((H > 1) ? (size_t)slice * E : 0);  // slice==head for L1
    const int rs = rowptr[n], re = rowptr[n + 1];
    const __half* fq = feat + col;
    float dsum = 0.f;
    float ax = 0.f, ay = 0.f, az = 0.f, aw = 0.f;
    int i = rs;
    for (; i + 2 <= re; i += 2) {
        float w0 = ws[i], w1 = ws[i + 1];
        int s0 = esrc[i], s1 = esrc[i + 1];
        union { uint2 u; __half2 h2[2]; } r0, r1;
        r0.u = *reinterpret_cast<const uint2*>(fq + (size_t)s0 * F);
        r1.u = *reinterpret_cast<const uint2*>(fq + (size_t)s1 * F);
        float2 a0 = __half22float2(r0.h2[0]), b0 = __half22float2(r0.h2[1]);
        float2 a1 = __half22float2(r1.h2[0]), b1 = __half22float2(r1.h2[1]);
        dsum += w0 + w1;
        ax += w0 * a0.x + w1 * a1.x;
        ay += w0 * a0.y + w1 * a1.y;
        az += w0 * b0.x + w1 * b1.x;
        aw += w0 * b0.y + w1 * b1.y;
    }
    if (i < re) {
        float wg = ws[i];
        int s = esrc[i];
        union { uint2 u; __half2 h2[2]; } r;
        r.u = *reinterpret_cast<const uint2*>(fq + (size_t)s * F);
        float2 a = __half22float2(r.h2[0]), b = __half22float2(r.h2[1]);
        dsum += wg;
        ax += wg * a.x; ay += wg * a.y; az += wg * b.x; aw += wg * b.y;
    }
    float inv = (re > rs) ? 1.f / dsum : 0.f;
    float4 bv = *reinterpret_cast<const float4*>(bias + col);
    float o0 = ax * inv + bv.x, o1 = ay * inv + bv.y;
    float o2 = az * inv + bv.z, o3 = aw * inv + bv.w;
    if constexpr (HOUT) {
        union { __half2 h2[2]; unsigned long long ull; } pk;
        pk.h2[0] = __floats2half2_rn(o0, o1);
        pk.h2[1] = __floats2half2_rn(o2, o3);
        __builtin_nontemporal_store(pk.ull,
            reinterpret_cast<unsigned long long*>((__half*)rst_ + (size_t)n * F + col));
    } else {
        f32x4 v = {o0, o1, o2, o3};
        __builtin_nontemporal_store(v,
            reinterpret_cast<f32x4*>((float*)rst_ + (size_t)n * F + col));
    }
}

// ---------- per-graph mean pooling (gid sorted -> segmented reduce) --------
__global__ void graph_start_kernel(const int* __restrict__ gid, int* __restrict__ start,
                                   int N, int G) {
    int g = blockIdx.x * blockDim.x + threadIdx.x;
    if (g > G) return;
    if (g == G) { start[G] = N; return; }
    int lo = 0, hi = N;
    while (lo < hi) {
        int mid = (lo + hi) >> 1;
        if (gid[mid] < g) lo = mid + 1; else hi = mid;
    }
    start[g] = lo;
}

__global__ void seg_pool_kernel(const float* __restrict__ h, const int* __restrict__ start,
                                float* __restrict__ out, int D) {
    int g = blockIdx.x;
    int d = threadIdx.x;
    int s = start[g], e = start[g + 1];
    float acc = 0.f;
    for (int n = s; n < e; ++n) acc += h[(size_t)n * D + d];
    out[(size_t)g * D + d] = acc / fmaxf((float)(e - s), 1.f);
}

extern "C" void kernel_launch(void* const* d_in, const int* in_sizes, int n_in,
                              void* d_out, int out_size, void* d_ws, size_t ws_size,
                              hipStream_t stream) {
    const float* x   = (const float*)d_in[0];
    const float* W1  = (const float*)d_in[1];
    const float* al1 = (const float*)d_in[2];
    const float* ar1 = (const float*)d_in[3];
    const float* b1  = (const float*)d_in[4];
    const float* W2  = (const float*)d_in[5];
    const float* al2 = (const float*)d_in[6];
    const float* ar2 = (const float*)d_in[7];
    const float* b2  = (const float*)d_in[8];
    const int* src   = (const int*)d_in[9];
    const int* dst   = (const int*)d_in[10];
    const int* gid   = (const int*)d_in[11];
    float* out = (float*)d_out;

    float* ws = (float*)d_ws;
    size_t off = 0;
    // ---- zero-initialized region ----
    int*   deg    = (int*)(ws + off); off += N_NODES;
    int*   cursor = (int*)(ws + off); off += N_NODES;
    float* el2    = ws + off;         off += N_NODES;   // atomic targets
    float* er2    = ws + off;         off += N_NODES;
    const size_t zeroN = off;
    // ---- write-before-read region (16B-aligned chunks) ----
    int* rowptr = (int*)(ws + off); off += N_NODES + 4;
    int* gstart = (int*)(ws + off); off += N_GRAPHS + 4;
    int* esrc   = (int*)(ws + off); off += N_EDGES;
    int* edst   = (int*)(ws + off); off += N_EDGES;
    float* w1buf = ws + off; off += (size_t)8 * N_EDGES;
    float* w2buf = ws + off; off += N_EDGES;
    __half* xh     = (__half*)(ws + off); off += (size_t)N_NODES * 128;   // 256 halves
    __half* w1t    = (__half*)(ws + off); off += 512 * 256 / 2;
    __half* w2t    = (__half*)(ws + off); off += 128 * 512 / 2;
    __half* feat1h = (__half*)(ws + off); off += (size_t)N_NODES * 256;   // 512 halves
    float*  el1    = ws + off; off += (size_t)N_NODES * 8;
    float*  er1    = ws + off; off += (size_t)N_NODES * 8;
    __half* rst1h  = (__half*)(ws + off); off += (size_t)N_NODES * 256;   // 512 halves
    __half* feat2h = (__half*)(ws + off); off += (size_t)N_NODES * 64;    // 128 halves
    float*  rst2   = ws + off; off += (size_t)N_NODES * 128;

    fill_zero<<<512, 256, 0, stream>>>(ws, (int)zeroN);

    // ---- CSR build + graph segment starts + fp16 conversions ----
    hist_kernel<<<(N_EDGES + 255) / 256, 256, 0, stream>>>(dst, deg, N_EDGES);
    scan_kernel<<<1, 1024, 0, stream>>>(deg, rowptr, N_NODES);
    scatter_kernel<<<(N_EDGES + 255) / 256, 256, 0, stream>>>(src, dst, rowptr, cursor, esrc, edst, N_EDGES);
    graph_start_kernel<<<1, 256, 0, stream>>>(gid, gstart, N_NODES, N_GRAPHS);
    f32_to_h<<<(N_NODES * 256 / 4 + 255) / 256, 256, 0, stream>>>(x, xh, N_NODES * 256 / 4);
    transpose_h<<<(256 * 512 + 255) / 256, 256, 0, stream>>>(W1, w1t, 256, 512);
    transpose_h<<<(512 * 128 + 255) / 256, 256, 0, stream>>>(W2, w2t, 512, 128);

    // ===== layer 1: H=8, D=64 =====
    dim3 g1((N_NODES + 127) / 128, 512 / 128);
    gemm_mfma<128, 128, 64, 64, 8, 64><<<g1, 256, 0, stream>>>(
        xh, w1t, feat1h, al1, ar1, el1, er1, N_NODES, 512, 256);
    edge_w8<<<(N_EDGES + 255) / 256, 256, 0, stream>>>(el1, er1, esrc, edst, w1buf, N_EDGES);
    node_aggr_w<8, 64, 64, true><<<(N_NODES / 16) * 8, 256, 0, stream>>>(
        feat1h, w1buf, rowptr, esrc, b1, rst1h, N_NODES, N_EDGES);

    // ===== layer 2: H=1, D=128 =====
    dim3 g2((N_NODES + 63) / 64, 128 / 128);
    gemm_mfma<64, 128, 32, 64, 1, 128><<<g2, 256, 0, stream>>>(
        rst1h, w2t, feat2h, al2, ar2, el2, er2, N_NODES, 128, 512);
    edge_w1<<<(N_EDGES + 255) / 256, 256, 0, stream>>>(el2, er2, esrc, edst, w2buf, N_EDGES);
    node_aggr_w<1, 128, 16, false><<<((N_NODES + 63) / 64) * 8, 256, 0, stream>>>(
        feat2h, w2buf, rowptr, esrc, b2, rst2, N_NODES, N_EDGES);

    // ===== readout: per-graph mean (segmented, no atomics) =====
    seg_pool_kernel<<<N_GRAPHS, 128, 0, stream>>>(rst2, gstart, out, 128);
}

// Round 10
// 250.772 us; speedup vs baseline: 1.2191x; 1.2191x over previous
//
#include <hip/hip_runtime.h>
#include <hip/hip_fp16.h>

#define N_NODES  20000
#define N_EDGES  320000
#define N_GRAPHS 128

typedef _Float16 half8 __attribute__((ext_vector_type(8)));
typedef float    f32x4 __attribute__((ext_vector_type(4)));

__global__ void fill_zero(float* __restrict__ p, int n) {
    int i = blockIdx.x * blockDim.x + threadIdx.x;
    int stride = gridDim.x * blockDim.x;
    for (; i < n; i += stride) p[i] = 0.f;
}

// ---------- f32 -> fp16 convert (4 elems/thread) ----------
__global__ void f32_to_h(const float* __restrict__ in, __half* __restrict__ o, int n4) {
    int i = blockIdx.x * blockDim.x + threadIdx.x;
    if (i >= n4) return;
    float4 v = *reinterpret_cast<const float4*>(&in[i * 4]);
    union { __half2 h2[2]; uint2 u; } pk;
    pk.h2[0] = __floats2half2_rn(v.x, v.y);
    pk.h2[1] = __floats2half2_rn(v.z, v.w);
    *reinterpret_cast<uint2*>(&o[i * 4]) = pk.u;
}

// ---------- W[R,C] f32 -> WT[C,R] fp16 ----------
__global__ void transpose_h(const float* __restrict__ W, __half* __restrict__ WT,
                            int R, int C) {
    int i = blockIdx.x * blockDim.x + threadIdx.x;
    if (i >= R * C) return;
    int r = i / C, c = i - r * C;
    WT[(size_t)c * R + r] = __float2half(W[i]);
}

// ---------- MFMA fp16 GEMM + fused el/er ----------
template <int BM, int BN, int WM, int WN, int H, int D>
__global__ __launch_bounds__(256) void gemm_mfma(
        const __half* __restrict__ A, const __half* __restrict__ BT,
        __half* __restrict__ C, const float* __restrict__ al,
        const float* __restrict__ ar, float* __restrict__ el,
        float* __restrict__ er, int Mm, int Nn, int Kk) {
    constexpr int BK  = 32;
    constexpr int MFR = WM / 16, NFR = WN / 16;
    constexpr int WCOLS = BN / WN;
    __shared__ __align__(16) __half As[BM * BK];
    __shared__ __align__(16) __half Bs[BN * BK];
    const int tid  = threadIdx.x;
    const int w    = tid >> 6, lane = tid & 63;
    const int wr   = w / WCOLS, wc = w % WCOLS;
    const int brow = blockIdx.x * BM;
    const int bcol = blockIdx.y * BN;
    const int lr   = lane & 15;
    const int lk   = (lane >> 4) * 8;

    f32x4 acc[MFR][NFR] = {};

    for (int k0 = 0; k0 < Kk; k0 += BK) {
        for (int c = tid; c < BM * 4; c += 256) {
            int r = c >> 2, ko = (c & 3) * 8;
            int gr = brow + r; if (gr >= Mm) gr = Mm - 1;
            int off = (r * BK + ko) ^ ((r & 7) << 3);
            *reinterpret_cast<uint4*>(&As[off]) =
                *reinterpret_cast<const uint4*>(&A[(size_t)gr * Kk + k0 + ko]);
        }
        for (int c = tid; c < BN * 4; c += 256) {
            int r = c >> 2, ko = (c & 3) * 8;
            int off = (r * BK + ko) ^ ((r & 7) << 3);
            *reinterpret_cast<uint4*>(&Bs[off]) =
                *reinterpret_cast<const uint4*>(&BT[(size_t)(bcol + r) * Kk + k0 + ko]);
        }
        __syncthreads();
        half8 af[MFR], bf[NFR];
#pragma unroll
        for (int m = 0; m < MFR; ++m) {
            int r = wr * WM + m * 16 + lr;
            af[m] = *reinterpret_cast<const half8*>(&As[(r * BK + lk) ^ ((r & 7) << 3)]);
        }
#pragma unroll
        for (int n = 0; n < NFR; ++n) {
            int r = wc * WN + n * 16 + lr;
            bf[n] = *reinterpret_cast<const half8*>(&Bs[(r * BK + lk) ^ ((r & 7) << 3)]);
        }
#pragma unroll
        for (int m = 0; m < MFR; ++m)
#pragma unroll
            for (int n = 0; n < NFR; ++n)
                acc[m][n] = __builtin_amdgcn_mfma_f32_16x16x32_f16(af[m], bf[n], acc[m][n], 0, 0, 0);
        __syncthreads();
    }

#pragma unroll
    for (int m = 0; m < MFR; ++m) {
        int r0 = brow + wr * WM + m * 16 + ((lane >> 4) << 2);
#pragma unroll
        for (int n = 0; n < NFR; ++n) {
            int cc = bcol + wc * WN + n * 16 + lr;
#pragma unroll
            for (int g = 0; g < 4; ++g)
                if (r0 + g < Mm) C[(size_t)(r0 + g) * Nn + cc] = __float2half(acc[m][n][g]);
        }
    }
    const int h = (bcol + wc * WN) / D;
    float alv[NFR], arv[NFR];
#pragma unroll
    for (int n = 0; n < NFR; ++n) {
        alv[n] = al[bcol + wc * WN + n * 16 + lr];
        arv[n] = ar[bcol + wc * WN + n * 16 + lr];
    }
#pragma unroll
    for (int m = 0; m < MFR; ++m) {
#pragma unroll
        for (int g = 0; g < 4; ++g) {
            float pl = 0.f, pr = 0.f;
#pragma unroll
            for (int n = 0; n < NFR; ++n) {
                pl += acc[m][n][g] * alv[n];
                pr += acc[m][n][g] * arv[n];
            }
            pl += __shfl_xor(pl, 1); pl += __shfl_xor(pl, 2);
            pl += __shfl_xor(pl, 4); pl += __shfl_xor(pl, 8);
            pr += __shfl_xor(pr, 1); pr += __shfl_xor(pr, 2);
            pr += __shfl_xor(pr, 4); pr += __shfl_xor(pr, 8);
            int gr = brow + wr * WM + m * 16 + ((lane >> 4) << 2) + g;
            if (lr == 0 && gr < Mm) {
                if constexpr (WN == D) {
                    el[(size_t)gr * H + h] = pl;
                    er[(size_t)gr * H + h] = pr;
                } else {
                    atomicAdd(&el[(size_t)gr * H + h], pl);
                    atomicAdd(&er[(size_t)gr * H + h], pr);
                }
            }
        }
    }
}

// ---------- CSR build: histogram -> scan -> scatter ----------
__global__ void hist_kernel(const int* __restrict__ dst, int* __restrict__ deg, int E) {
    int e = blockIdx.x * blockDim.x + threadIdx.x;
    if (e >= E) return;
    atomicAdd(&deg[dst[e]], 1);
}

__global__ void scan_kernel(const int* __restrict__ deg, int* __restrict__ rowptr, int n) {
    __shared__ int partial[1024];
    const int t = threadIdx.x;
    const int CH = (n + 1023) / 1024;
    const int base = t * CH;
    int local = 0;
    for (int i = 0; i < CH; ++i)
        if (base + i < n) local += deg[base + i];
    partial[t] = local;
    __syncthreads();
    for (int o = 1; o < 1024; o <<= 1) {
        int v = (t >= o) ? partial[t - o] : 0;
        __syncthreads();
        partial[t] += v;
        __syncthreads();
    }
    int run = (t == 0) ? 0 : partial[t - 1];
    for (int i = 0; i < CH; ++i) {
        if (base + i <= n) rowptr[base + i] = run;
        if (base + i < n) run += deg[base + i];
    }
}

__global__ void scatter_kernel(const int* __restrict__ src, const int* __restrict__ dst,
                               const int* __restrict__ rowptr, int* __restrict__ cursor,
                               int* __restrict__ esrc, int* __restrict__ edst, int E) {
    int e = blockIdx.x * blockDim.x + threadIdx.x;
    if (e >= E) return;
    int d = dst[e];
    int pos = rowptr[d] + atomicAdd(&cursor[d], 1);
    esrc[pos] = src[e];
    edst[pos] = d;
}

// ---------- edge-weight precompute ----------
__global__ void edge_w8(const float* __restrict__ el, const float* __restrict__ er,
                        const int* __restrict__ esrc, const int* __restrict__ edst,
                        float* __restrict__ w, int E) {
    int p = blockIdx.x * blockDim.x + threadIdx.x;
    if (p >= E) return;
    int s = esrc[p], d = edst[p];
    float4 l0 = *reinterpret_cast<const float4*>(&el[s * 8]);
    float4 l1 = *reinterpret_cast<const float4*>(&el[s * 8 + 4]);
    float4 r0 = *reinterpret_cast<const float4*>(&er[d * 8]);
    float4 r1 = *reinterpret_cast<const float4*>(&er[d * 8 + 4]);
    float xs[8] = {l0.x + r0.x, l0.y + r0.y, l0.z + r0.z, l0.w + r0.w,
                   l1.x + r1.x, l1.y + r1.y, l1.z + r1.z, l1.w + r1.w};
#pragma unroll
    for (int h = 0; h < 8; ++h) {
        float x = xs[h];
        x = (x > 0.f) ? x : 0.2f * x;
        w[(size_t)h * E + p] = __expf(x);
    }
}

__global__ void edge_w1(const float* __restrict__ el, const float* __restrict__ er,
                        const int* __restrict__ esrc, const int* __restrict__ edst,
                        float* __restrict__ w, int E) {
    int p = blockIdx.x * blockDim.x + threadIdx.x;
    if (p >= E) return;
    float x = el[esrc[p]] + er[edst[p]];
    x = (x > 0.f) ? x : 0.2f * x;
    w[p] = __expf(x);
}

// ---------- per-node GAT aggregation: precomputed weights ----------
template <int H, int D, int CPS, bool HOUT>
__global__ void node_aggr_w(const __half* __restrict__ feat, const float* __restrict__ wbuf,
                            const int* __restrict__ rowptr, const int* __restrict__ esrc,
                            const float* __restrict__ bias, void* __restrict__ rst_,
                            int N, int E) {
    constexpr int F   = H * D;
    constexpr int TPN = CPS / 4;
    constexpr int NPB = 256 / TPN;
    const int slice  = blockIdx.x & 7;
    const int nchunk = blockIdx.x >> 3;
    const int tid = threadIdx.x;
    const int n  = nchunk * NPB + tid / TPN;
    if (n >= N) return;
    const int col = (slice * TPN + (tid % TPN)) * 4;
    const float* ws = wbuf + ((H > 1) ? (size_t)slice * E : 0);  // slice==head for L1
    const int rs = rowptr[n], re = rowptr[n + 1];
    const __half* fq = feat + col;
    float dsum = 0.f;
    float ax = 0.f, ay = 0.f, az = 0.f, aw = 0.f;
    int i = rs;
    for (; i + 2 <= re; i += 2) {
        float w0 = ws[i], w1 = ws[i + 1];
        int s0 = esrc[i], s1 = esrc[i + 1];
        union { uint2 u; __half2 h2[2]; } r0, r1;
        r0.u = *reinterpret_cast<const uint2*>(fq + (size_t)s0 * F);
        r1.u = *reinterpret_cast<const uint2*>(fq + (size_t)s1 * F);
        float2 a0 = __half22float2(r0.h2[0]), b0 = __half22float2(r0.h2[1]);
        float2 a1 = __half22float2(r1.h2[0]), b1 = __half22float2(r1.h2[1]);
        dsum += w0 + w1;
        ax += w0 * a0.x + w1 * a1.x;
        ay += w0 * a0.y + w1 * a1.y;
        az += w0 * b0.x + w1 * b1.x;
        aw += w0 * b0.y + w1 * b1.y;
    }
    if (i < re) {
        float wg = ws[i];
        int s = esrc[i];
        union { uint2 u; __half2 h2[2]; } r;
        r.u = *reinterpret_cast<const uint2*>(fq + (size_t)s * F);
        float2 a = __half22float2(r.h2[0]), b = __half22float2(r.h2[1]);
        dsum += wg;
        ax += wg * a.x; ay += wg * a.y; az += wg * b.x; aw += wg * b.y;
    }
    float inv = (re > rs) ? 1.f / dsum : 0.f;
    float4 bv = *reinterpret_cast<const float4*>(bias + col);
    float o0 = ax * inv + bv.x, o1 = ay * inv + bv.y;
    float o2 = az * inv + bv.z, o3 = aw * inv + bv.w;
    if constexpr (HOUT) {
        union { __half2 h2[2]; uint2 u; } pk;
        pk.h2[0] = __floats2half2_rn(o0, o1);
        pk.h2[1] = __floats2half2_rn(o2, o3);
        *reinterpret_cast<uint2*>((__half*)rst_ + (size_t)n * F + col) = pk.u;
    } else {
        *reinterpret_cast<float4*>((float*)rst_ + (size_t)n * F + col) =
            make_float4(o0, o1, o2, o3);
    }
}

// ---------- per-graph mean pooling (sorted gid -> segmented reduce) --------
__global__ void graph_start_kernel(const int* __restrict__ gid, int* __restrict__ start,
                                   int N, int G) {
    int g = blockIdx.x * blockDim.x + threadIdx.x;
    if (g > G) return;
    if (g == G) { start[G] = N; return; }
    int lo = 0, hi = N;
    while (lo < hi) {
        int mid = (lo + hi) >> 1;
        if (gid[mid] < g) lo = mid + 1; else hi = mid;
    }
    start[g] = lo;
}

// one block per graph, 512 threads = 4 node-lanes x 128 dims; LDS combine.
__global__ __launch_bounds__(512) void seg_pool_kernel(
        const float* __restrict__ h, const int* __restrict__ start,
        float* __restrict__ out, int D) {
    __shared__ float part[3][128];
    int g = blockIdx.x;
    int d = threadIdx.x & 127;
    int j = threadIdx.x >> 7;           // 0..3
    int s = start[g], e = start[g + 1];
    float acc = 0.f;
    for (int n = s + j; n < e; n += 4) acc += h[(size_t)n * D + d];
    if (j > 0) part[j - 1][d] = acc;
    __syncthreads();
    if (j == 0) {
        acc += part[0][d] + part[1][d] + part[2][d];
        out[(size_t)g * D + d] = acc / fmaxf((float)(e - s), 1.f);
    }
}

extern "C" void kernel_launch(void* const* d_in, const int* in_sizes, int n_in,
                              void* d_out, int out_size, void* d_ws, size_t ws_size,
                              hipStream_t stream) {
    const float* x   = (const float*)d_in[0];
    const float* W1  = (const float*)d_in[1];
    const float* al1 = (const float*)d_in[2];
    const float* ar1 = (const float*)d_in[3];
    const float* b1  = (const float*)d_in[4];
    const float* W2  = (const float*)d_in[5];
    const float* al2 = (const float*)d_in[6];
    const float* ar2 = (const float*)d_in[7];
    const float* b2  = (const float*)d_in[8];
    const int* src   = (const int*)d_in[9];
    const int* dst   = (const int*)d_in[10];
    const int* gid   = (const int*)d_in[11];
    float* out = (float*)d_out;

    float* ws = (float*)d_ws;
    size_t off = 0;
    // ---- zero-initialized region ----
    int*   deg    = (int*)(ws + off); off += N_NODES;
    int*   cursor = (int*)(ws + off); off += N_NODES;
    float* el2    = ws + off;         off += N_NODES;   // atomic targets
    float* er2    = ws + off;         off += N_NODES;
    const size_t zeroN = off;
    // ---- write-before-read region (16B-aligned chunks) ----
    int* rowptr = (int*)(ws + off); off += N_NODES + 4;
    int* gstart = (int*)(ws + off); off += N_GRAPHS + 4;
    int* esrc   = (int*)(ws + off); off += N_EDGES;
    int* edst   = (int*)(ws + off); off += N_EDGES;
    float* w1buf = ws + off; off += (size_t)8 * N_EDGES;
    float* w2buf = ws + off; off += N_EDGES;
    __half* xh     = (__half*)(ws + off); off += (size_t)N_NODES * 128;   // 256 halves
    __half* w1t    = (__half*)(ws + off); off += 512 * 256 / 2;
    __half* w2t    = (__half*)(ws + off); off += 128 * 512 / 2;
    __half* feat1h = (__half*)(ws + off); off += (size_t)N_NODES * 256;   // 512 halves
    float*  el1    = ws + off; off += (size_t)N_NODES * 8;
    float*  er1    = ws + off; off += (size_t)N_NODES * 8;
    __half* rst1h  = (__half*)(ws + off); off += (size_t)N_NODES * 256;   // 512 halves
    __half* feat2h = (__half*)(ws + off); off += (size_t)N_NODES * 64;    // 128 halves
    float*  rst2   = ws + off; off += (size_t)N_NODES * 128;

    fill_zero<<<512, 256, 0, stream>>>(ws, (int)zeroN);

    // ---- CSR build + graph segment starts + fp16 conversions ----
    hist_kernel<<<(N_EDGES + 255) / 256, 256, 0, stream>>>(dst, deg, N_EDGES);
    scan_kernel<<<1, 1024, 0, stream>>>(deg, rowptr, N_NODES);
    scatter_kernel<<<(N_EDGES + 255) / 256, 256, 0, stream>>>(src, dst, rowptr, cursor, esrc, edst, N_EDGES);
    graph_start_kernel<<<1, 256, 0, stream>>>(gid, gstart, N_NODES, N_GRAPHS);
    f32_to_h<<<(N_NODES * 256 / 4 + 255) / 256, 256, 0, stream>>>(x, xh, N_NODES * 256 / 4);
    transpose_h<<<(256 * 512 + 255) / 256, 256, 0, stream>>>(W1, w1t, 256, 512);
    transpose_h<<<(512 * 128 + 255) / 256, 256, 0, stream>>>(W2, w2t, 512, 128);

    // ===== layer 1: H=8, D=64 =====
    dim3 g1((N_NODES + 127) / 128, 512 / 128);
    gemm_mfma<128, 128, 64, 64, 8, 64><<<g1, 256, 0, stream>>>(
        xh, w1t, feat1h, al1, ar1, el1, er1, N_NODES, 512, 256);
    edge_w8<<<(N_EDGES + 255) / 256, 256, 0, stream>>>(el1, er1, esrc, edst, w1buf, N_EDGES);
    node_aggr_w<8, 64, 64, true><<<(N_NODES / 16) * 8, 256, 0, stream>>>(
        feat1h, w1buf, rowptr, esrc, b1, rst1h, N_NODES, N_EDGES);

    // ===== layer 2: H=1, D=128 =====
    dim3 g2((N_NODES + 63) / 64, 128 / 128);
    gemm_mfma<64, 128, 32, 64, 1, 128><<<g2, 256, 0, stream>>>(
        rst1h, w2t, feat2h, al2, ar2, el2, er2, N_NODES, 128, 512);
    edge_w1<<<(N_EDGES + 255) / 256, 256, 0, stream>>>(el2, er2, esrc, edst, w2buf, N_EDGES);
    node_aggr_w<1, 128, 16, false><<<((N_NODES + 63) / 64) * 8, 256, 0, stream>>>(
        feat2h, w2buf, rowptr, esrc, b2, rst2, N_NODES, N_EDGES);

    // ===== readout: per-graph mean (segmented, no atomics) =====
    seg_pool_kernel<<<N_GRAPHS, 512, 0, stream>>>(rst2, gstart, out, 128);
}

// Round 11
// 221.429 us; speedup vs baseline: 1.3807x; 1.1325x over previous
//
#include <hip/hip_runtime.h>
#include <hip/hip_fp16.h>

#define N_NODES  20000
#define N_EDGES  320000
#define N_GRAPHS 128

typedef _Float16 half8 __attribute__((ext_vector_type(8)));
typedef float    f32x4 __attribute__((ext_vector_type(4)));

__global__ void fill_zero(float* __restrict__ p, int n) {
    int i = blockIdx.x * blockDim.x + threadIdx.x;
    int stride = gridDim.x * blockDim.x;
    for (; i < n; i += stride) p[i] = 0.f;
}

// ---------- f32 -> fp16 convert (4 elems/thread) ----------
__global__ void f32_to_h(const float* __restrict__ in, __half* __restrict__ o, int n4) {
    int i = blockIdx.x * blockDim.x + threadIdx.x;
    if (i >= n4) return;
    float4 v = *reinterpret_cast<const float4*>(&in[i * 4]);
    union { __half2 h2[2]; uint2 u; } pk;
    pk.h2[0] = __floats2half2_rn(v.x, v.y);
    pk.h2[1] = __floats2half2_rn(v.z, v.w);
    *reinterpret_cast<uint2*>(&o[i * 4]) = pk.u;
}

// ---------- W[R,C] f32 -> WT[C,R] fp16 ----------
__global__ void transpose_h(const float* __restrict__ W, __half* __restrict__ WT,
                            int R, int C) {
    int i = blockIdx.x * blockDim.x + threadIdx.x;
    if (i >= R * C) return;
    int r = i / C, c = i - r * C;
    WT[(size_t)c * R + r] = __float2half(W[i]);
}

// ---------- MFMA fp16 GEMM + fused el/er ----------
template <int BM, int BN, int WM, int WN, int H, int D>
__global__ __launch_bounds__(256) void gemm_mfma(
        const __half* __restrict__ A, const __half* __restrict__ BT,
        __half* __restrict__ C, const float* __restrict__ al,
        const float* __restrict__ ar, float* __restrict__ el,
        float* __restrict__ er, int Mm, int Nn, int Kk) {
    constexpr int BK  = 32;
    constexpr int MFR = WM / 16, NFR = WN / 16;
    constexpr int WCOLS = BN / WN;
    __shared__ __align__(16) __half As[BM * BK];
    __shared__ __align__(16) __half Bs[BN * BK];
    const int tid  = threadIdx.x;
    const int w    = tid >> 6, lane = tid & 63;
    const int wr   = w / WCOLS, wc = w % WCOLS;
    const int brow = blockIdx.x * BM;
    const int bcol = blockIdx.y * BN;
    const int lr   = lane & 15;
    const int lk   = (lane >> 4) * 8;

    f32x4 acc[MFR][NFR] = {};

    for (int k0 = 0; k0 < Kk; k0 += BK) {
        for (int c = tid; c < BM * 4; c += 256) {
            int r = c >> 2, ko = (c & 3) * 8;
            int gr = brow + r; if (gr >= Mm) gr = Mm - 1;
            int off = (r * BK + ko) ^ ((r & 7) << 3);
            *reinterpret_cast<uint4*>(&As[off]) =
                *reinterpret_cast<const uint4*>(&A[(size_t)gr * Kk + k0 + ko]);
        }
        for (int c = tid; c < BN * 4; c += 256) {
            int r = c >> 2, ko = (c & 3) * 8;
            int off = (r * BK + ko) ^ ((r & 7) << 3);
            *reinterpret_cast<uint4*>(&Bs[off]) =
                *reinterpret_cast<const uint4*>(&BT[(size_t)(bcol + r) * Kk + k0 + ko]);
        }
        __syncthreads();
        half8 af[MFR], bf[NFR];
#pragma unroll
        for (int m = 0; m < MFR; ++m) {
            int r = wr * WM + m * 16 + lr;
            af[m] = *reinterpret_cast<const half8*>(&As[(r * BK + lk) ^ ((r & 7) << 3)]);
        }
#pragma unroll
        for (int n = 0; n < NFR; ++n) {
            int r = wc * WN + n * 16 + lr;
            bf[n] = *reinterpret_cast<const half8*>(&Bs[(r * BK + lk) ^ ((r & 7) << 3)]);
        }
#pragma unroll
        for (int m = 0; m < MFR; ++m)
#pragma unroll
            for (int n = 0; n < NFR; ++n)
                acc[m][n] = __builtin_amdgcn_mfma_f32_16x16x32_f16(af[m], bf[n], acc[m][n], 0, 0, 0);
        __syncthreads();
    }

#pragma unroll
    for (int m = 0; m < MFR; ++m) {
        int r0 = brow + wr * WM + m * 16 + ((lane >> 4) << 2);
#pragma unroll
        for (int n = 0; n < NFR; ++n) {
            int cc = bcol + wc * WN + n * 16 + lr;
#pragma unroll
            for (int g = 0; g < 4; ++g)
                if (r0 + g < Mm) C[(size_t)(r0 + g) * Nn + cc] = __float2half(acc[m][n][g]);
        }
    }
    const int h = (bcol + wc * WN) / D;
    float alv[NFR], arv[NFR];
#pragma unroll
    for (int n = 0; n < NFR; ++n) {
        alv[n] = al[bcol + wc * WN + n * 16 + lr];
        arv[n] = ar[bcol + wc * WN + n * 16 + lr];
    }
#pragma unroll
    for (int m = 0; m < MFR; ++m) {
#pragma unroll
        for (int g = 0; g < 4; ++g) {
            float pl = 0.f, pr = 0.f;
#pragma unroll
            for (int n = 0; n < NFR; ++n) {
                pl += acc[m][n][g] * alv[n];
                pr += acc[m][n][g] * arv[n];
            }
            pl += __shfl_xor(pl, 1); pl += __shfl_xor(pl, 2);
            pl += __shfl_xor(pl, 4); pl += __shfl_xor(pl, 8);
            pr += __shfl_xor(pr, 1); pr += __shfl_xor(pr, 2);
            pr += __shfl_xor(pr, 4); pr += __shfl_xor(pr, 8);
            int gr = brow + wr * WM + m * 16 + ((lane >> 4) << 2) + g;
            if (lr == 0 && gr < Mm) {
                if constexpr (WN == D) {
                    el[(size_t)gr * H + h] = pl;
                    er[(size_t)gr * H + h] = pr;
                } else {
                    atomicAdd(&el[(size_t)gr * H + h], pl);
                    atomicAdd(&er[(size_t)gr * H + h], pr);
                }
            }
        }
    }
}

// ---------- CSR build: histogram -> scan -> scatter ----------
__global__ void hist_kernel(const int* __restrict__ dst, int* __restrict__ deg, int E) {
    int e = blockIdx.x * blockDim.x + threadIdx.x;
    if (e >= E) return;
    atomicAdd(&deg[dst[e]], 1);
}

__global__ void scan_kernel(const int* __restrict__ deg, int* __restrict__ rowptr, int n) {
    __shared__ int partial[1024];
    const int t = threadIdx.x;
    const int CH = (n + 1023) / 1024;
    const int base = t * CH;
    int local = 0;
    for (int i = 0; i < CH; ++i)
        if (base + i < n) local += deg[base + i];
    partial[t] = local;
    __syncthreads();
    for (int o = 1; o < 1024; o <<= 1) {
        int v = (t >= o) ? partial[t - o] : 0;
        __syncthreads();
        partial[t] += v;
        __syncthreads();
    }
    int run = (t == 0) ? 0 : partial[t - 1];
    for (int i = 0; i < CH; ++i) {
        if (base + i <= n) rowptr[base + i] = run;
        if (base + i < n) run += deg[base + i];
    }
}

__global__ void scatter_kernel(const int* __restrict__ src, const int* __restrict__ dst,
                               const int* __restrict__ rowptr, int* __restrict__ cursor,
                               int* __restrict__ esrc, int* __restrict__ edst, int E) {
    int e = blockIdx.x * blockDim.x + threadIdx.x;
    if (e >= E) return;
    int d = dst[e];
    int pos = rowptr[d] + atomicAdd(&cursor[d], 1);
    esrc[pos] = src[e];
    edst[pos] = d;
}

// ---------- edge-weight precompute; layer-1 layout [pos][h] (32B/edge) -----
__global__ void edge_w8(const float* __restrict__ el, const float* __restrict__ er,
                        const int* __restrict__ esrc, const int* __restrict__ edst,
                        float* __restrict__ w, int E) {
    int p = blockIdx.x * blockDim.x + threadIdx.x;
    if (p >= E) return;
    int s = esrc[p], d = edst[p];
    float4 l0 = *reinterpret_cast<const float4*>(&el[s * 8]);
    float4 l1 = *reinterpret_cast<const float4*>(&el[s * 8 + 4]);
    float4 r0 = *reinterpret_cast<const float4*>(&er[d * 8]);
    float4 r1 = *reinterpret_cast<const float4*>(&er[d * 8 + 4]);
    float xs[8] = {l0.x + r0.x, l0.y + r0.y, l0.z + r0.z, l0.w + r0.w,
                   l1.x + r1.x, l1.y + r1.y, l1.z + r1.z, l1.w + r1.w};
    float o[8];
#pragma unroll
    for (int h = 0; h < 8; ++h) {
        float x = xs[h];
        x = (x > 0.f) ? x : 0.2f * x;
        o[h] = __expf(x);
    }
    *reinterpret_cast<float4*>(&w[(size_t)p * 8])     = make_float4(o[0], o[1], o[2], o[3]);
    *reinterpret_cast<float4*>(&w[(size_t)p * 8 + 4]) = make_float4(o[4], o[5], o[6], o[7]);
}

__global__ void edge_w1(const float* __restrict__ el, const float* __restrict__ er,
                        const int* __restrict__ esrc, const int* __restrict__ edst,
                        float* __restrict__ w, int E) {
    int p = blockIdx.x * blockDim.x + threadIdx.x;
    if (p >= E) return;
    float x = el[esrc[p]] + er[edst[p]];
    x = (x > 0.f) ? x : 0.2f * x;
    w[p] = __expf(x);
}

// ---------- per-node aggregation: wave-per-node, full-row 16B/lane gathers -
// F halves per row; LPN = F/8 lanes cover a row; NPW = 64/LPN nodes/wave.
// Each edge: 1 contiguous (NPW rows) gather burst + broadcast esrc/w reads.
template <int F, int H, bool HOUT>
__global__ __launch_bounds__(256) void node_aggr_wave(
        const __half* __restrict__ feat, const float* __restrict__ wbuf,
        const int* __restrict__ rowptr, const int* __restrict__ esrc,
        const float* __restrict__ bias, void* __restrict__ rst_, int N) {
    constexpr int LPN = F / 8;          // lanes per node (L1: 64, L2: 16)
    constexpr int NPW = 64 / LPN;       // nodes per wave (L1: 1,  L2: 4)
    constexpr int D   = F / H;
    const int wid  = (blockIdx.x * blockDim.x + threadIdx.x) >> 6;
    const int lane = threadIdx.x & 63;
    const int n    = wid * NPW + lane / LPN;
    if (n >= N) return;
    const int col = (lane % LPN) * 8;
    const int h   = col / D;
    const int rs = rowptr[n], re = rowptr[n + 1];
    const __half* fq = feat + col;

    float acc[8] = {};
    float dsum = 0.f;
    int i = rs;
    for (; i + 2 <= re; i += 2) {
        int s0 = esrc[i], s1 = esrc[i + 1];
        float w0 = (H > 1) ? wbuf[(size_t)i * H + h] : wbuf[i];
        float w1 = (H > 1) ? wbuf[(size_t)(i + 1) * H + h] : wbuf[i + 1];
        union { uint4 u; __half2 h2[4]; } r0, r1;
        r0.u = *reinterpret_cast<const uint4*>(fq + (size_t)s0 * F);
        r1.u = *reinterpret_cast<const uint4*>(fq + (size_t)s1 * F);
        dsum += w0 + w1;
#pragma unroll
        for (int k = 0; k < 4; ++k) {
            float2 f0 = __half22float2(r0.h2[k]);
            float2 f1 = __half22float2(r1.h2[k]);
            acc[2 * k]     += w0 * f0.x + w1 * f1.x;
            acc[2 * k + 1] += w0 * f0.y + w1 * f1.y;
        }
    }
    if (i < re) {
        int s = esrc[i];
        float w = (H > 1) ? wbuf[(size_t)i * H + h] : wbuf[i];
        union { uint4 u; __half2 h2[4]; } r;
        r.u = *reinterpret_cast<const uint4*>(fq + (size_t)s * F);
        dsum += w;
#pragma unroll
        for (int k = 0; k < 4; ++k) {
            float2 f = __half22float2(r.h2[k]);
            acc[2 * k]     += w * f.x;
            acc[2 * k + 1] += w * f.y;
        }
    }
    float inv = (re > rs) ? 1.f / dsum : 0.f;
    float4 b0 = *reinterpret_cast<const float4*>(bias + col);
    float4 b1 = *reinterpret_cast<const float4*>(bias + col + 4);
    float o[8] = {acc[0] * inv + b0.x, acc[1] * inv + b0.y,
                  acc[2] * inv + b0.z, acc[3] * inv + b0.w,
                  acc[4] * inv + b1.x, acc[5] * inv + b1.y,
                  acc[6] * inv + b1.z, acc[7] * inv + b1.w};
    if constexpr (HOUT) {
        union { __half2 h2[4]; uint4 u; } pk;
        pk.h2[0] = __floats2half2_rn(o[0], o[1]);
        pk.h2[1] = __floats2half2_rn(o[2], o[3]);
        pk.h2[2] = __floats2half2_rn(o[4], o[5]);
        pk.h2[3] = __floats2half2_rn(o[6], o[7]);
        *reinterpret_cast<uint4*>((__half*)rst_ + (size_t)n * F + col) = pk.u;
    } else {
        float* op = (float*)rst_ + (size_t)n * F + col;
        *reinterpret_cast<float4*>(op)     = make_float4(o[0], o[1], o[2], o[3]);
        *reinterpret_cast<float4*>(op + 4) = make_float4(o[4], o[5], o[6], o[7]);
    }
}

// ---------- per-graph mean pooling (sorted gid -> segmented reduce) --------
__global__ void graph_start_kernel(const int* __restrict__ gid, int* __restrict__ start,
                                   int N, int G) {
    int g = blockIdx.x * blockDim.x + threadIdx.x;
    if (g > G) return;
    if (g == G) { start[G] = N; return; }
    int lo = 0, hi = N;
    while (lo < hi) {
        int mid = (lo + hi) >> 1;
        if (gid[mid] < g) lo = mid + 1; else hi = mid;
    }
    start[g] = lo;
}

// one block per graph, 512 threads = 4 node-lanes x 128 dims; LDS combine.
__global__ __launch_bounds__(512) void seg_pool_kernel(
        const float* __restrict__ h, const int* __restrict__ start,
        float* __restrict__ out, int D) {
    __shared__ float part[3][128];
    int g = blockIdx.x;
    int d = threadIdx.x & 127;
    int j = threadIdx.x >> 7;           // 0..3
    int s = start[g], e = start[g + 1];
    float acc = 0.f;
    for (int n = s + j; n < e; n += 4) acc += h[(size_t)n * D + d];
    if (j > 0) part[j - 1][d] = acc;
    __syncthreads();
    if (j == 0) {
        acc += part[0][d] + part[1][d] + part[2][d];
        out[(size_t)g * D + d] = acc / fmaxf((float)(e - s), 1.f);
    }
}

extern "C" void kernel_launch(void* const* d_in, const int* in_sizes, int n_in,
                              void* d_out, int out_size, void* d_ws, size_t ws_size,
                              hipStream_t stream) {
    const float* x   = (const float*)d_in[0];
    const float* W1  = (const float*)d_in[1];
    const float* al1 = (const float*)d_in[2];
    const float* ar1 = (const float*)d_in[3];
    const float* b1  = (const float*)d_in[4];
    const float* W2  = (const float*)d_in[5];
    const float* al2 = (const float*)d_in[6];
    const float* ar2 = (const float*)d_in[7];
    const float* b2  = (const float*)d_in[8];
    const int* src   = (const int*)d_in[9];
    const int* dst   = (const int*)d_in[10];
    const int* gid   = (const int*)d_in[11];
    float* out = (float*)d_out;

    float* ws = (float*)d_ws;
    size_t off = 0;
    // ---- zero-initialized region ----
    int*   deg    = (int*)(ws + off); off += N_NODES;
    int*   cursor = (int*)(ws + off); off += N_NODES;
    float* el2    = ws + off;         off += N_NODES;   // atomic targets
    float* er2    = ws + off;         off += N_NODES;
    const size_t zeroN = off;
    // ---- write-before-read region (16B-aligned chunks) ----
    int* rowptr = (int*)(ws + off); off += N_NODES + 4;
    int* gstart = (int*)(ws + off); off += N_GRAPHS + 4;
    int* esrc   = (int*)(ws + off); off += N_EDGES;
    int* edst   = (int*)(ws + off); off += N_EDGES;
    float* w1buf = ws + off; off += (size_t)8 * N_EDGES;   // [pos][h]
    float* w2buf = ws + off; off += N_EDGES;
    __half* xh     = (__half*)(ws + off); off += (size_t)N_NODES * 128;   // 256 halves
    __half* w1t    = (__half*)(ws + off); off += 512 * 256 / 2;
    __half* w2t    = (__half*)(ws + off); off += 128 * 512 / 2;
    __half* feat1h = (__half*)(ws + off); off += (size_t)N_NODES * 256;   // 512 halves
    float*  el1    = ws + off; off += (size_t)N_NODES * 8;
    float*  er1    = ws + off; off += (size_t)N_NODES * 8;
    __half* rst1h  = (__half*)(ws + off); off += (size_t)N_NODES * 256;   // 512 halves
    __half* feat2h = (__half*)(ws + off); off += (size_t)N_NODES * 64;    // 128 halves
    float*  rst2   = ws + off; off += (size_t)N_NODES * 128;

    fill_zero<<<512, 256, 0, stream>>>(ws, (int)zeroN);

    // ---- CSR build + graph segment starts + fp16 conversions ----
    hist_kernel<<<(N_EDGES + 255) / 256, 256, 0, stream>>>(dst, deg, N_EDGES);
    scan_kernel<<<1, 1024, 0, stream>>>(deg, rowptr, N_NODES);
    scatter_kernel<<<(N_EDGES + 255) / 256, 256, 0, stream>>>(src, dst, rowptr, cursor, esrc, edst, N_EDGES);
    graph_start_kernel<<<1, 256, 0, stream>>>(gid, gstart, N_NODES, N_GRAPHS);
    f32_to_h<<<(N_NODES * 256 / 4 + 255) / 256, 256, 0, stream>>>(x, xh, N_NODES * 256 / 4);
    transpose_h<<<(256 * 512 + 255) / 256, 256, 0, stream>>>(W1, w1t, 256, 512);
    transpose_h<<<(512 * 128 + 255) / 256, 256, 0, stream>>>(W2, w2t, 512, 128);

    // ===== layer 1: H=8, D=64 =====
    dim3 g1((N_NODES + 127) / 128, 512 / 128);
    gemm_mfma<128, 128, 64, 64, 8, 64><<<g1, 256, 0, stream>>>(
        xh, w1t, feat1h, al1, ar1, el1, er1, N_NODES, 512, 256);
    edge_w8<<<(N_EDGES + 255) / 256, 256, 0, stream>>>(el1, er1, esrc, edst, w1buf, N_EDGES);
    // one wave per node (F=512): 20000 waves -> 5000 blocks
    node_aggr_wave<512, 8, true><<<(N_NODES * 64 + 255) / 256, 256, 0, stream>>>(
        feat1h, w1buf, rowptr, esrc, b1, rst1h, N_NODES);

    // ===== layer 2: H=1, D=128 =====
    dim3 g2((N_NODES + 63) / 64, 128 / 128);
    gemm_mfma<64, 128, 32, 64, 1, 128><<<g2, 256, 0, stream>>>(
        rst1h, w2t, feat2h, al2, ar2, el2, er2, N_NODES, 128, 512);
    edge_w1<<<(N_EDGES + 255) / 256, 256, 0, stream>>>(el2, er2, esrc, edst, w2buf, N_EDGES);
    // 4 nodes per wave (F=128): 5000 waves -> 1250 blocks
    node_aggr_wave<128, 1, false><<<(N_NODES * 16 + 255) / 256, 256, 0, stream>>>(
        feat2h, w2buf, rowptr, esrc, b2, rst2, N_NODES);

    // ===== readout: per-graph mean (segmented, no atomics) =====
    seg_pool_kernel<<<N_GRAPHS, 512, 0, stream>>>(rst2, gstart, out, 128);
}

// Round 12
// 208.914 us; speedup vs baseline: 1.4634x; 1.0599x over previous
//
#include <hip/hip_runtime.h>
#include <hip/hip_fp16.h>

#define N_NODES  20000
#define N_EDGES  320000
#define N_GRAPHS 128

typedef _Float16 half8 __attribute__((ext_vector_type(8)));
typedef float    f32x4 __attribute__((ext_vector_type(4)));

__global__ void fill_zero(float* __restrict__ p, int n) {
    int i = blockIdx.x * blockDim.x + threadIdx.x;
    int stride = gridDim.x * blockDim.x;
    for (; i < n; i += stride) p[i] = 0.f;
}

// ---------- both weight transposes in one launch (f32 -> fp16 T) ----------
__global__ void transpose_both(const float* __restrict__ W1, const float* __restrict__ W2,
                               __half* __restrict__ w1t, __half* __restrict__ w2t) {
    int i = blockIdx.x * blockDim.x + threadIdx.x;
    if (i < 256 * 512) {
        int r = i >> 9, c = i & 511;
        w1t[c * 256 + r] = __float2half(W1[i]);
    } else {
        int j = i - 256 * 512;
        if (j < 512 * 128) {
            int r = j >> 7, c = j & 127;
            w2t[c * 512 + r] = __float2half(W2[j]);
        }
    }
}

// ---------- MFMA fp16 GEMM + fused el/er; A may be f32 (converted in stage) -
template <int BM, int BN, int WM, int WN, int H, int D, bool AF32>
__global__ __launch_bounds__(256) void gemm_mfma(
        const void* __restrict__ A_, const __half* __restrict__ BT,
        __half* __restrict__ C, const float* __restrict__ al,
        const float* __restrict__ ar, float* __restrict__ el,
        float* __restrict__ er, int Mm, int Nn, int Kk) {
    constexpr int BK  = 32;
    constexpr int MFR = WM / 16, NFR = WN / 16;
    constexpr int WCOLS = BN / WN;
    __shared__ __align__(16) __half As[BM * BK];
    __shared__ __align__(16) __half Bs[BN * BK];
    const int tid  = threadIdx.x;
    const int w    = tid >> 6, lane = tid & 63;
    const int wr   = w / WCOLS, wc = w % WCOLS;
    const int brow = blockIdx.x * BM;
    const int bcol = blockIdx.y * BN;
    const int lr   = lane & 15;
    const int lk   = (lane >> 4) * 8;

    f32x4 acc[MFR][NFR] = {};

    for (int k0 = 0; k0 < Kk; k0 += BK) {
        for (int c = tid; c < BM * 4; c += 256) {
            int r = c >> 2, ko = (c & 3) * 8;
            int gr = brow + r; if (gr >= Mm) gr = Mm - 1;
            int off = (r * BK + ko) ^ ((r & 7) << 3);
            if constexpr (AF32) {
                const float* ap = (const float*)A_ + (size_t)gr * Kk + k0 + ko;
                float4 v0 = *reinterpret_cast<const float4*>(ap);
                float4 v1 = *reinterpret_cast<const float4*>(ap + 4);
                union { __half2 h2[4]; uint4 u; } pk;
                pk.h2[0] = __floats2half2_rn(v0.x, v0.y);
                pk.h2[1] = __floats2half2_rn(v0.z, v0.w);
                pk.h2[2] = __floats2half2_rn(v1.x, v1.y);
                pk.h2[3] = __floats2half2_rn(v1.z, v1.w);
                *reinterpret_cast<uint4*>(&As[off]) = pk.u;
            } else {
                *reinterpret_cast<uint4*>(&As[off]) =
                    *reinterpret_cast<const uint4*>((const __half*)A_ + (size_t)gr * Kk + k0 + ko);
            }
        }
        for (int c = tid; c < BN * 4; c += 256) {
            int r = c >> 2, ko = (c & 3) * 8;
            int off = (r * BK + ko) ^ ((r & 7) << 3);
            *reinterpret_cast<uint4*>(&Bs[off]) =
                *reinterpret_cast<const uint4*>(&BT[(size_t)(bcol + r) * Kk + k0 + ko]);
        }
        __syncthreads();
        half8 af[MFR], bf[NFR];
#pragma unroll
        for (int m = 0; m < MFR; ++m) {
            int r = wr * WM + m * 16 + lr;
            af[m] = *reinterpret_cast<const half8*>(&As[(r * BK + lk) ^ ((r & 7) << 3)]);
        }
#pragma unroll
        for (int n = 0; n < NFR; ++n) {
            int r = wc * WN + n * 16 + lr;
            bf[n] = *reinterpret_cast<const half8*>(&Bs[(r * BK + lk) ^ ((r & 7) << 3)]);
        }
#pragma unroll
        for (int m = 0; m < MFR; ++m)
#pragma unroll
            for (int n = 0; n < NFR; ++n)
                acc[m][n] = __builtin_amdgcn_mfma_f32_16x16x32_f16(af[m], bf[n], acc[m][n], 0, 0, 0);
        __syncthreads();
    }

#pragma unroll
    for (int m = 0; m < MFR; ++m) {
        int r0 = brow + wr * WM + m * 16 + ((lane >> 4) << 2);
#pragma unroll
        for (int n = 0; n < NFR; ++n) {
            int cc = bcol + wc * WN + n * 16 + lr;
#pragma unroll
            for (int g = 0; g < 4; ++g)
                if (r0 + g < Mm) C[(size_t)(r0 + g) * Nn + cc] = __float2half(acc[m][n][g]);
        }
    }
    const int h = (bcol + wc * WN) / D;
    float alv[NFR], arv[NFR];
#pragma unroll
    for (int n = 0; n < NFR; ++n) {
        alv[n] = al[bcol + wc * WN + n * 16 + lr];
        arv[n] = ar[bcol + wc * WN + n * 16 + lr];
    }
#pragma unroll
    for (int m = 0; m < MFR; ++m) {
#pragma unroll
        for (int g = 0; g < 4; ++g) {
            float pl = 0.f, pr = 0.f;
#pragma unroll
            for (int n = 0; n < NFR; ++n) {
                pl += acc[m][n][g] * alv[n];
                pr += acc[m][n][g] * arv[n];
            }
            pl += __shfl_xor(pl, 1); pl += __shfl_xor(pl, 2);
            pl += __shfl_xor(pl, 4); pl += __shfl_xor(pl, 8);
            pr += __shfl_xor(pr, 1); pr += __shfl_xor(pr, 2);
            pr += __shfl_xor(pr, 4); pr += __shfl_xor(pr, 8);
            int gr = brow + wr * WM + m * 16 + ((lane >> 4) << 2) + g;
            if (lr == 0 && gr < Mm) {
                if constexpr (WN == D) {
                    el[(size_t)gr * H + h] = pl;
                    er[(size_t)gr * H + h] = pr;
                } else {
                    atomicAdd(&el[(size_t)gr * H + h], pl);
                    atomicAdd(&er[(size_t)gr * H + h], pr);
                }
            }
        }
    }
}

// ---------- CSR build: histogram -> scan -> scatter ----------
__global__ void hist_kernel(const int* __restrict__ dst, int* __restrict__ deg, int E) {
    int e = blockIdx.x * blockDim.x + threadIdx.x;
    if (e >= E) return;
    atomicAdd(&deg[dst[e]], 1);
}

__global__ void scan_kernel(const int* __restrict__ deg, int* __restrict__ rowptr, int n) {
    __shared__ int partial[1024];
    const int t = threadIdx.x;
    const int CH = (n + 1023) / 1024;
    const int base = t * CH;
    int local = 0;
    for (int i = 0; i < CH; ++i)
        if (base + i < n) local += deg[base + i];
    partial[t] = local;
    __syncthreads();
    for (int o = 1; o < 1024; o <<= 1) {
        int v = (t >= o) ? partial[t - o] : 0;
        __syncthreads();
        partial[t] += v;
        __syncthreads();
    }
    int run = (t == 0) ? 0 : partial[t - 1];
    for (int i = 0; i < CH; ++i) {
        if (base + i <= n) rowptr[base + i] = run;
        if (base + i < n) run += deg[base + i];
    }
}

__global__ void scatter_kernel(const int* __restrict__ src, const int* __restrict__ dst,
                               const int* __restrict__ rowptr, int* __restrict__ cursor,
                               int* __restrict__ esrc, int* __restrict__ edst, int E) {
    int e = blockIdx.x * blockDim.x + threadIdx.x;
    if (e >= E) return;
    int d = dst[e];
    int pos = rowptr[d] + atomicAdd(&cursor[d], 1);
    esrc[pos] = src[e];
    edst[pos] = d;
}

// ---------- edge-weight precompute; layer-1 layout [pos][h] (32B/edge) -----
__global__ void edge_w8(const float* __restrict__ el, const float* __restrict__ er,
                        const int* __restrict__ esrc, const int* __restrict__ edst,
                        float* __restrict__ w, int E) {
    int p = blockIdx.x * blockDim.x + threadIdx.x;
    if (p >= E) return;
    int s = esrc[p], d = edst[p];
    float4 l0 = *reinterpret_cast<const float4*>(&el[s * 8]);
    float4 l1 = *reinterpret_cast<const float4*>(&el[s * 8 + 4]);
    float4 r0 = *reinterpret_cast<const float4*>(&er[d * 8]);
    float4 r1 = *reinterpret_cast<const float4*>(&er[d * 8 + 4]);
    float xs[8] = {l0.x + r0.x, l0.y + r0.y, l0.z + r0.z, l0.w + r0.w,
                   l1.x + r1.x, l1.y + r1.y, l1.z + r1.z, l1.w + r1.w};
    float o[8];
#pragma unroll
    for (int h = 0; h < 8; ++h) {
        float x = xs[h];
        x = (x > 0.f) ? x : 0.2f * x;
        o[h] = __expf(x);
    }
    *reinterpret_cast<float4*>(&w[(size_t)p * 8])     = make_float4(o[0], o[1], o[2], o[3]);
    *reinterpret_cast<float4*>(&w[(size_t)p * 8 + 4]) = make_float4(o[4], o[5], o[6], o[7]);
}

__global__ void edge_w1(const float* __restrict__ el, const float* __restrict__ er,
                        const int* __restrict__ esrc, const int* __restrict__ edst,
                        float* __restrict__ w, int E) {
    int p = blockIdx.x * blockDim.x + threadIdx.x;
    if (p >= E) return;
    float x = el[esrc[p]] + er[edst[p]];
    x = (x > 0.f) ? x : 0.2f * x;
    w[p] = __expf(x);
}

// ---------- per-node aggregation: wave-per-node, 16B/lane, unroll x4 -------
template <int F, int H, bool HOUT>
__global__ __launch_bounds__(256) void node_aggr_wave(
        const __half* __restrict__ feat, const float* __restrict__ wbuf,
        const int* __restrict__ rowptr, const int* __restrict__ esrc,
        const float* __restrict__ bias, void* __restrict__ rst_, int N) {
    constexpr int LPN = F / 8;
    constexpr int NPW = 64 / LPN;
    constexpr int D   = F / H;
    const int wid  = (blockIdx.x * blockDim.x + threadIdx.x) >> 6;
    const int lane = threadIdx.x & 63;
    const int n    = wid * NPW + lane / LPN;
    if (n >= N) return;
    const int col = (lane % LPN) * 8;
    const int h   = col / D;
    const int rs = rowptr[n], re = rowptr[n + 1];
    const __half* fq = feat + col;

    float acc[8] = {};
    float dsum = 0.f;
    int i = rs;
    for (; i + 4 <= re; i += 4) {
        int s0 = esrc[i], s1 = esrc[i + 1], s2 = esrc[i + 2], s3 = esrc[i + 3];
        float w0 = (H > 1) ? wbuf[(size_t)i * H + h]       : wbuf[i];
        float w1 = (H > 1) ? wbuf[(size_t)(i + 1) * H + h] : wbuf[i + 1];
        float w2 = (H > 1) ? wbuf[(size_t)(i + 2) * H + h] : wbuf[i + 2];
        float w3 = (H > 1) ? wbuf[(size_t)(i + 3) * H + h] : wbuf[i + 3];
        union { uint4 u; __half2 h2[4]; } r0, r1, r2, r3;
        r0.u = *reinterpret_cast<const uint4*>(fq + (size_t)s0 * F);
        r1.u = *reinterpret_cast<const uint4*>(fq + (size_t)s1 * F);
        r2.u = *reinterpret_cast<const uint4*>(fq + (size_t)s2 * F);
        r3.u = *reinterpret_cast<const uint4*>(fq + (size_t)s3 * F);
        dsum += (w0 + w1) + (w2 + w3);
#pragma unroll
        for (int k = 0; k < 4; ++k) {
            float2 f0 = __half22float2(r0.h2[k]);
            float2 f1 = __half22float2(r1.h2[k]);
            float2 f2 = __half22float2(r2.h2[k]);
            float2 f3 = __half22float2(r3.h2[k]);
            acc[2 * k]     += w0 * f0.x + w1 * f1.x + w2 * f2.x + w3 * f3.x;
            acc[2 * k + 1] += w0 * f0.y + w1 * f1.y + w2 * f2.y + w3 * f3.y;
        }
    }
    for (; i < re; ++i) {
        int s = esrc[i];
        float w = (H > 1) ? wbuf[(size_t)i * H + h] : wbuf[i];
        union { uint4 u; __half2 h2[4]; } r;
        r.u = *reinterpret_cast<const uint4*>(fq + (size_t)s * F);
        dsum += w;
#pragma unroll
        for (int k = 0; k < 4; ++k) {
            float2 f = __half22float2(r.h2[k]);
            acc[2 * k]     += w * f.x;
            acc[2 * k + 1] += w * f.y;
        }
    }
    float inv = (re > rs) ? 1.f / dsum : 0.f;
    float4 b0 = *reinterpret_cast<const float4*>(bias + col);
    float4 b1 = *reinterpret_cast<const float4*>(bias + col + 4);
    float o[8] = {acc[0] * inv + b0.x, acc[1] * inv + b0.y,
                  acc[2] * inv + b0.z, acc[3] * inv + b0.w,
                  acc[4] * inv + b1.x, acc[5] * inv + b1.y,
                  acc[6] * inv + b1.z, acc[7] * inv + b1.w};
    if constexpr (HOUT) {
        union { __half2 h2[4]; uint4 u; } pk;
        pk.h2[0] = __floats2half2_rn(o[0], o[1]);
        pk.h2[1] = __floats2half2_rn(o[2], o[3]);
        pk.h2[2] = __floats2half2_rn(o[4], o[5]);
        pk.h2[3] = __floats2half2_rn(o[6], o[7]);
        *reinterpret_cast<uint4*>((__half*)rst_ + (size_t)n * F + col) = pk.u;
    } else {
        float* op = (float*)rst_ + (size_t)n * F + col;
        *reinterpret_cast<float4*>(op)     = make_float4(o[0], o[1], o[2], o[3]);
        *reinterpret_cast<float4*>(op + 4) = make_float4(o[4], o[5], o[6], o[7]);
    }
}

// ---------- per-graph mean pooling (sorted gid -> segmented reduce) --------
__global__ void graph_start_kernel(const int* __restrict__ gid, int* __restrict__ start,
                                   int N, int G) {
    int g = blockIdx.x * blockDim.x + threadIdx.x;
    if (g > G) return;
    if (g == G) { start[G] = N; return; }
    int lo = 0, hi = N;
    while (lo < hi) {
        int mid = (lo + hi) >> 1;
        if (gid[mid] < g) lo = mid + 1; else hi = mid;
    }
    start[g] = lo;
}

// one block per graph, 1024 threads = 8 node-lanes x 128 dims; LDS combine.
__global__ __launch_bounds__(1024) void seg_pool_kernel(
        const float* __restrict__ h, const int* __restrict__ start,
        float* __restrict__ out, int D) {
    __shared__ float part[7][128];
    int g = blockIdx.x;
    int d = threadIdx.x & 127;
    int j = threadIdx.x >> 7;           // 0..7
    int s = start[g], e = start[g + 1];
    float acc = 0.f;
    for (int n = s + j; n < e; n += 8) acc += h[(size_t)n * D + d];
    if (j > 0) part[j - 1][d] = acc;
    __syncthreads();
    if (j == 0) {
#pragma unroll
        for (int k = 0; k < 7; ++k) acc += part[k][d];
        out[(size_t)g * D + d] = acc / fmaxf((float)(e - s), 1.f);
    }
}

extern "C" void kernel_launch(void* const* d_in, const int* in_sizes, int n_in,
                              void* d_out, int out_size, void* d_ws, size_t ws_size,
                              hipStream_t stream) {
    const float* x   = (const float*)d_in[0];
    const float* W1  = (const float*)d_in[1];
    const float* al1 = (const float*)d_in[2];
    const float* ar1 = (const float*)d_in[3];
    const float* b1  = (const float*)d_in[4];
    const float* W2  = (const float*)d_in[5];
    const float* al2 = (const float*)d_in[6];
    const float* ar2 = (const float*)d_in[7];
    const float* b2  = (const float*)d_in[8];
    const int* src   = (const int*)d_in[9];
    const int* dst   = (const int*)d_in[10];
    const int* gid   = (const int*)d_in[11];
    float* out = (float*)d_out;

    float* ws = (float*)d_ws;
    size_t off = 0;
    // ---- zero-initialized region ----
    int*   deg    = (int*)(ws + off); off += N_NODES;
    int*   cursor = (int*)(ws + off); off += N_NODES;
    float* el2    = ws + off;         off += N_NODES;   // atomic targets
    float* er2    = ws + off;         off += N_NODES;
    const size_t zeroN = off;
    // ---- write-before-read region (16B-aligned chunks) ----
    int* rowptr = (int*)(ws + off); off += N_NODES + 4;
    int* gstart = (int*)(ws + off); off += N_GRAPHS + 4;
    int* esrc   = (int*)(ws + off); off += N_EDGES;
    int* edst   = (int*)(ws + off); off += N_EDGES;
    float* w1buf = ws + off; off += (size_t)8 * N_EDGES;   // [pos][h]
    float* w2buf = ws + off; off += N_EDGES;
    __half* w1t    = (__half*)(ws + off); off += 512 * 256 / 2;
    __half* w2t    = (__half*)(ws + off); off += 128 * 512 / 2;
    __half* feat1h = (__half*)(ws + off); off += (size_t)N_NODES * 256;   // 512 halves
    float*  el1    = ws + off; off += (size_t)N_NODES * 8;
    float*  er1    = ws + off; off += (size_t)N_NODES * 8;
    __half* rst1h  = (__half*)(ws + off); off += (size_t)N_NODES * 256;   // 512 halves
    __half* feat2h = (__half*)(ws + off); off += (size_t)N_NODES * 64;    // 128 halves
    float*  rst2   = ws + off; off += (size_t)N_NODES * 128;

    fill_zero<<<208, 256, 0, stream>>>(ws, (int)zeroN);

    // ---- CSR build + graph segment starts + weight transposes ----
    hist_kernel<<<(N_EDGES + 255) / 256, 256, 0, stream>>>(dst, deg, N_EDGES);
    scan_kernel<<<1, 1024, 0, stream>>>(deg, rowptr, N_NODES);
    scatter_kernel<<<(N_EDGES + 255) / 256, 256, 0, stream>>>(src, dst, rowptr, cursor, esrc, edst, N_EDGES);
    graph_start_kernel<<<1, 256, 0, stream>>>(gid, gstart, N_NODES, N_GRAPHS);
    transpose_both<<<(256 * 512 + 512 * 128 + 255) / 256, 256, 0, stream>>>(W1, W2, w1t, w2t);

    // ===== layer 1: H=8, D=64; GEMM reads f32 x directly =====
    dim3 g1((N_NODES + 127) / 128, 512 / 128);
    gemm_mfma<128, 128, 64, 64, 8, 64, true><<<g1, 256, 0, stream>>>(
        x, w1t, feat1h, al1, ar1, el1, er1, N_NODES, 512, 256);
    edge_w8<<<(N_EDGES + 255) / 256, 256, 0, stream>>>(el1, er1, esrc, edst, w1buf, N_EDGES);
    node_aggr_wave<512, 8, true><<<(N_NODES * 64 + 255) / 256, 256, 0, stream>>>(
        feat1h, w1buf, rowptr, esrc, b1, rst1h, N_NODES);

    // ===== layer 2: H=1, D=128 =====
    dim3 g2((N_NODES + 63) / 64, 128 / 128);
    gemm_mfma<64, 128, 32, 64, 1, 128, false><<<g2, 256, 0, stream>>>(
        rst1h, w2t, feat2h, al2, ar2, el2, er2, N_NODES, 128, 512);
    edge_w1<<<(N_EDGES + 255) / 256, 256, 0, stream>>>(el2, er2, esrc, edst, w2buf, N_EDGES);
    node_aggr_wave<128, 1, false><<<(N_NODES * 16 + 255) / 256, 256, 0, stream>>>(
        feat2h, w2buf, rowptr, esrc, b2, rst2, N_NODES);

    // ===== readout: per-graph mean (segmented, no atomics) =====
    seg_pool_kernel<<<N_GRAPHS, 1024, 0, stream>>>(rst2, gstart, out, 128);
}

// Round 13
// 197.965 us; speedup vs baseline: 1.5443x; 1.0553x over previous
//
#include <hip/hip_runtime.h>
#include <hip/hip_fp16.h>

#define N_NODES  20000
#define N_EDGES  320000
#define N_GRAPHS 128

typedef _Float16 half8 __attribute__((ext_vector_type(8)));
typedef float    f32x4 __attribute__((ext_vector_type(4)));

__global__ void fill_zero(int* __restrict__ p, int n) {
    int i = blockIdx.x * blockDim.x + threadIdx.x;
    int stride = gridDim.x * blockDim.x;
    for (; i < n; i += stride) p[i] = 0;
}

// ---------- setup: both weight transposes (f32 -> fp16 T) + graph starts ---
__global__ void setup_misc(const float* __restrict__ W1, const float* __restrict__ W2,
                           __half* __restrict__ w1t, __half* __restrict__ w2t,
                           const int* __restrict__ gid, int* __restrict__ gstart) {
    int i = blockIdx.x * blockDim.x + threadIdx.x;
    if (i < 256 * 512) {
        int r = i >> 9, c = i & 511;
        w1t[c * 256 + r] = __float2half(W1[i]);
    } else if (i < 256 * 512 + 512 * 128) {
        int j = i - 256 * 512;
        int r = j >> 7, c = j & 127;
        w2t[c * 512 + r] = __float2half(W2[j]);
    } else {
        int g = i - (256 * 512 + 512 * 128);
        if (g <= N_GRAPHS) {
            if (g == N_GRAPHS) { gstart[N_GRAPHS] = N_NODES; return; }
            int lo = 0, hi = N_NODES;
            while (lo < hi) {
                int mid = (lo + hi) >> 1;
                if (gid[mid] < g) lo = mid + 1; else hi = mid;
            }
            gstart[g] = lo;
        }
    }
}

// ---------- MFMA fp16 GEMM + fused el/er; A may be f32 (converted in stage) -
template <int BM, int BN, int WM, int WN, int H, int D, bool AF32>
__global__ __launch_bounds__(256) void gemm_mfma(
        const void* __restrict__ A_, const __half* __restrict__ BT,
        __half* __restrict__ C, const float* __restrict__ al,
        const float* __restrict__ ar, float* __restrict__ el,
        float* __restrict__ er, int Mm, int Nn, int Kk) {
    constexpr int BK  = 32;
    constexpr int MFR = WM / 16, NFR = WN / 16;
    constexpr int WCOLS = BN / WN;
    __shared__ __align__(16) __half As[BM * BK];
    __shared__ __align__(16) __half Bs[BN * BK];
    const int tid  = threadIdx.x;
    const int w    = tid >> 6, lane = tid & 63;
    const int wr   = w / WCOLS, wc = w % WCOLS;
    const int brow = blockIdx.x * BM;
    const int bcol = blockIdx.y * BN;
    const int lr   = lane & 15;
    const int lk   = (lane >> 4) * 8;

    f32x4 acc[MFR][NFR] = {};

    for (int k0 = 0; k0 < Kk; k0 += BK) {
        for (int c = tid; c < BM * 4; c += 256) {
            int r = c >> 2, ko = (c & 3) * 8;
            int gr = brow + r; if (gr >= Mm) gr = Mm - 1;
            int off = (r * BK + ko) ^ ((r & 7) << 3);
            if constexpr (AF32) {
                const float* ap = (const float*)A_ + (size_t)gr * Kk + k0 + ko;
                float4 v0 = *reinterpret_cast<const float4*>(ap);
                float4 v1 = *reinterpret_cast<const float4*>(ap + 4);
                union { __half2 h2[4]; uint4 u; } pk;
                pk.h2[0] = __floats2half2_rn(v0.x, v0.y);
                pk.h2[1] = __floats2half2_rn(v0.z, v0.w);
                pk.h2[2] = __floats2half2_rn(v1.x, v1.y);
                pk.h2[3] = __floats2half2_rn(v1.z, v1.w);
                *reinterpret_cast<uint4*>(&As[off]) = pk.u;
            } else {
                *reinterpret_cast<uint4*>(&As[off]) =
                    *reinterpret_cast<const uint4*>((const __half*)A_ + (size_t)gr * Kk + k0 + ko);
            }
        }
        for (int c = tid; c < BN * 4; c += 256) {
            int r = c >> 2, ko = (c & 3) * 8;
            int off = (r * BK + ko) ^ ((r & 7) << 3);
            *reinterpret_cast<uint4*>(&Bs[off]) =
                *reinterpret_cast<const uint4*>(&BT[(size_t)(bcol + r) * Kk + k0 + ko]);
        }
        __syncthreads();
        half8 af[MFR], bf[NFR];
#pragma unroll
        for (int m = 0; m < MFR; ++m) {
            int r = wr * WM + m * 16 + lr;
            af[m] = *reinterpret_cast<const half8*>(&As[(r * BK + lk) ^ ((r & 7) << 3)]);
        }
#pragma unroll
        for (int n = 0; n < NFR; ++n) {
            int r = wc * WN + n * 16 + lr;
            bf[n] = *reinterpret_cast<const half8*>(&Bs[(r * BK + lk) ^ ((r & 7) << 3)]);
        }
#pragma unroll
        for (int m = 0; m < MFR; ++m)
#pragma unroll
            for (int n = 0; n < NFR; ++n)
                acc[m][n] = __builtin_amdgcn_mfma_f32_16x16x32_f16(af[m], bf[n], acc[m][n], 0, 0, 0);
        __syncthreads();
    }

#pragma unroll
    for (int m = 0; m < MFR; ++m) {
        int r0 = brow + wr * WM + m * 16 + ((lane >> 4) << 2);
#pragma unroll
        for (int n = 0; n < NFR; ++n) {
            int cc = bcol + wc * WN + n * 16 + lr;
#pragma unroll
            for (int g = 0; g < 4; ++g)
                if (r0 + g < Mm) C[(size_t)(r0 + g) * Nn + cc] = __float2half(acc[m][n][g]);
        }
    }
    const int h = (bcol + wc * WN) / D;
    float alv[NFR], arv[NFR];
#pragma unroll
    for (int n = 0; n < NFR; ++n) {
        alv[n] = al[bcol + wc * WN + n * 16 + lr];
        arv[n] = ar[bcol + wc * WN + n * 16 + lr];
    }
#pragma unroll
    for (int m = 0; m < MFR; ++m) {
#pragma unroll
        for (int g = 0; g < 4; ++g) {
            float pl = 0.f, pr = 0.f;
#pragma unroll
            for (int n = 0; n < NFR; ++n) {
                pl += acc[m][n][g] * alv[n];
                pr += acc[m][n][g] * arv[n];
            }
            pl += __shfl_xor(pl, 1); pl += __shfl_xor(pl, 2);
            pl += __shfl_xor(pl, 4); pl += __shfl_xor(pl, 8);
            pr += __shfl_xor(pr, 1); pr += __shfl_xor(pr, 2);
            pr += __shfl_xor(pr, 4); pr += __shfl_xor(pr, 8);
            int gr = brow + wr * WM + m * 16 + ((lane >> 4) << 2) + g;
            if (lr == 0 && gr < Mm) {
                if constexpr (WN == D) {
                    el[(size_t)gr * H + h] = pl;
                    er[(size_t)gr * H + h] = pr;
                } else {
                    atomicAdd(&el[(size_t)gr * H + h], pl);
                    atomicAdd(&er[(size_t)gr * H + h], pr);
                }
            }
        }
    }
}

// ---------- CSR build: histogram -> scan -> scatter ----------
__global__ void hist_kernel(const int* __restrict__ dst, int* __restrict__ deg, int E) {
    int e = blockIdx.x * blockDim.x + threadIdx.x;
    if (e >= E) return;
    atomicAdd(&deg[dst[e]], 1);
}

__global__ void scan_kernel(const int* __restrict__ deg, int* __restrict__ rowptr, int n) {
    __shared__ int partial[1024];
    const int t = threadIdx.x;
    const int CH = (n + 1023) / 1024;
    const int base = t * CH;
    int local = 0;
    for (int i = 0; i < CH; ++i)
        if (base + i < n) local += deg[base + i];
    partial[t] = local;
    __syncthreads();
    for (int o = 1; o < 1024; o <<= 1) {
        int v = (t >= o) ? partial[t - o] : 0;
        __syncthreads();
        partial[t] += v;
        __syncthreads();
    }
    int run = (t == 0) ? 0 : partial[t - 1];
    for (int i = 0; i < CH; ++i) {
        if (base + i <= n) rowptr[base + i] = run;
        if (base + i < n) run += deg[base + i];
    }
}

__global__ void scatter_kernel(const int* __restrict__ src, const int* __restrict__ dst,
                               const int* __restrict__ rowptr, int* __restrict__ cursor,
                               int* __restrict__ esrc, int E) {
    int e = blockIdx.x * blockDim.x + threadIdx.x;
    if (e >= E) return;
    int d = dst[e];
    int pos = rowptr[d] + atomicAdd(&cursor[d], 1);
    esrc[pos] = src[e];
}

// ---------- per-node aggregation: wave-per-node, inline edge weights -------
// F halves/row; LPN=F/8 lanes cover a row; NPW=64/LPN nodes/wave.
// Per edge: 16B/lane contiguous feat burst + small L2-resident el gather;
// lrelu+exp computed in-loop (VALU headroom under the BW bound).
template <int F, int H, bool HOUT>
__global__ __launch_bounds__(256) void node_aggr_wave(
        const __half* __restrict__ feat, const float* __restrict__ el,
        const float* __restrict__ er, const int* __restrict__ rowptr,
        const int* __restrict__ esrc, const float* __restrict__ bias,
        void* __restrict__ rst_, int N) {
    constexpr int LPN = F / 8;
    constexpr int NPW = 64 / LPN;
    constexpr int D   = F / H;
    const int wid  = (blockIdx.x * blockDim.x + threadIdx.x) >> 6;
    const int lane = threadIdx.x & 63;
    const int n    = wid * NPW + lane / LPN;
    if (n >= N) return;
    const int col = (lane % LPN) * 8;
    const int h   = col / D;
    const float ern = er[(size_t)n * H + h];
    const int rs = rowptr[n], re = rowptr[n + 1];
    const __half* fq = feat + col;

    float acc[8] = {};
    float dsum = 0.f;
    int i = rs;
    for (; i + 4 <= re; i += 4) {
        int s0 = esrc[i], s1 = esrc[i + 1], s2 = esrc[i + 2], s3 = esrc[i + 3];
        float x0 = el[(size_t)s0 * H + h] + ern;
        float x1 = el[(size_t)s1 * H + h] + ern;
        float x2 = el[(size_t)s2 * H + h] + ern;
        float x3 = el[(size_t)s3 * H + h] + ern;
        x0 = (x0 > 0.f) ? x0 : 0.2f * x0;
        x1 = (x1 > 0.f) ? x1 : 0.2f * x1;
        x2 = (x2 > 0.f) ? x2 : 0.2f * x2;
        x3 = (x3 > 0.f) ? x3 : 0.2f * x3;
        float w0 = __expf(x0), w1 = __expf(x1), w2 = __expf(x2), w3 = __expf(x3);
        union { uint4 u; __half2 h2[4]; } r0, r1, r2, r3;
        r0.u = *reinterpret_cast<const uint4*>(fq + (size_t)s0 * F);
        r1.u = *reinterpret_cast<const uint4*>(fq + (size_t)s1 * F);
        r2.u = *reinterpret_cast<const uint4*>(fq + (size_t)s2 * F);
        r3.u = *reinterpret_cast<const uint4*>(fq + (size_t)s3 * F);
        dsum += (w0 + w1) + (w2 + w3);
#pragma unroll
        for (int k = 0; k < 4; ++k) {
            float2 f0 = __half22float2(r0.h2[k]);
            float2 f1 = __half22float2(r1.h2[k]);
            float2 f2 = __half22float2(r2.h2[k]);
            float2 f3 = __half22float2(r3.h2[k]);
            acc[2 * k]     += w0 * f0.x + w1 * f1.x + w2 * f2.x + w3 * f3.x;
            acc[2 * k + 1] += w0 * f0.y + w1 * f1.y + w2 * f2.y + w3 * f3.y;
        }
    }
    for (; i < re; ++i) {
        int s = esrc[i];
        float x = el[(size_t)s * H + h] + ern;
        x = (x > 0.f) ? x : 0.2f * x;
        float w = __expf(x);
        union { uint4 u; __half2 h2[4]; } r;
        r.u = *reinterpret_cast<const uint4*>(fq + (size_t)s * F);
        dsum += w;
#pragma unroll
        for (int k = 0; k < 4; ++k) {
            float2 f = __half22float2(r.h2[k]);
            acc[2 * k]     += w * f.x;
            acc[2 * k + 1] += w * f.y;
        }
    }
    float inv = (re > rs) ? 1.f / dsum : 0.f;
    float4 b0 = *reinterpret_cast<const float4*>(bias + col);
    float4 b1 = *reinterpret_cast<const float4*>(bias + col + 4);
    float o[8] = {acc[0] * inv + b0.x, acc[1] * inv + b0.y,
                  acc[2] * inv + b0.z, acc[3] * inv + b0.w,
                  acc[4] * inv + b1.x, acc[5] * inv + b1.y,
                  acc[6] * inv + b1.z, acc[7] * inv + b1.w};
    if constexpr (HOUT) {
        union { __half2 h2[4]; uint4 u; } pk;
        pk.h2[0] = __floats2half2_rn(o[0], o[1]);
        pk.h2[1] = __floats2half2_rn(o[2], o[3]);
        pk.h2[2] = __floats2half2_rn(o[4], o[5]);
        pk.h2[3] = __floats2half2_rn(o[6], o[7]);
        *reinterpret_cast<uint4*>((__half*)rst_ + (size_t)n * F + col) = pk.u;
    } else {
        float* op = (float*)rst_ + (size_t)n * F + col;
        *reinterpret_cast<float4*>(op)     = make_float4(o[0], o[1], o[2], o[3]);
        *reinterpret_cast<float4*>(op + 4) = make_float4(o[4], o[5], o[6], o[7]);
    }
}

// ---------- per-graph mean pooling (sorted gid -> segmented reduce) --------
__global__ __launch_bounds__(1024) void seg_pool_kernel(
        const float* __restrict__ h, const int* __restrict__ start,
        float* __restrict__ out, int D) {
    __shared__ float part[7][128];
    int g = blockIdx.x;
    int d = threadIdx.x & 127;
    int j = threadIdx.x >> 7;           // 0..7
    int s = start[g], e = start[g + 1];
    float acc = 0.f;
    for (int n = s + j; n < e; n += 8) acc += h[(size_t)n * D + d];
    if (j > 0) part[j - 1][d] = acc;
    __syncthreads();
    if (j == 0) {
#pragma unroll
        for (int k = 0; k < 7; ++k) acc += part[k][d];
        out[(size_t)g * D + d] = acc / fmaxf((float)(e - s), 1.f);
    }
}

extern "C" void kernel_launch(void* const* d_in, const int* in_sizes, int n_in,
                              void* d_out, int out_size, void* d_ws, size_t ws_size,
                              hipStream_t stream) {
    const float* x   = (const float*)d_in[0];
    const float* W1  = (const float*)d_in[1];
    const float* al1 = (const float*)d_in[2];
    const float* ar1 = (const float*)d_in[3];
    const float* b1  = (const float*)d_in[4];
    const float* W2  = (const float*)d_in[5];
    const float* al2 = (const float*)d_in[6];
    const float* ar2 = (const float*)d_in[7];
    const float* b2  = (const float*)d_in[8];
    const int* src   = (const int*)d_in[9];
    const int* dst   = (const int*)d_in[10];
    const int* gid   = (const int*)d_in[11];
    float* out = (float*)d_out;

    float* ws = (float*)d_ws;
    size_t off = 0;
    // ---- zero-initialized region (deg + cursor only) ----
    int* deg    = (int*)(ws + off); off += N_NODES;
    int* cursor = (int*)(ws + off); off += N_NODES;
    const size_t zeroN = off;
    // ---- write-before-read region (16B-aligned chunks) ----
    int* rowptr = (int*)(ws + off); off += N_NODES + 4;
    int* gstart = (int*)(ws + off); off += N_GRAPHS + 4;
    int* esrc   = (int*)(ws + off); off += N_EDGES;
    __half* w1t    = (__half*)(ws + off); off += 512 * 256 / 2;
    __half* w2t    = (__half*)(ws + off); off += 128 * 512 / 2;
    __half* feat1h = (__half*)(ws + off); off += (size_t)N_NODES * 256;   // 512 halves
    float*  el1    = ws + off; off += (size_t)N_NODES * 8;
    float*  er1    = ws + off; off += (size_t)N_NODES * 8;
    __half* rst1h  = (__half*)(ws + off); off += (size_t)N_NODES * 256;   // 512 halves
    __half* feat2h = (__half*)(ws + off); off += (size_t)N_NODES * 64;    // 128 halves
    float*  el2    = ws + off; off += N_NODES;
    float*  er2    = ws + off; off += N_NODES;
    float*  rst2   = ws + off; off += (size_t)N_NODES * 128;

    fill_zero<<<40, 256, 0, stream>>>((int*)ws, (int)zeroN);

    // ---- CSR build + setup (transposes + graph starts) ----
    hist_kernel<<<(N_EDGES + 255) / 256, 256, 0, stream>>>(dst, deg, N_EDGES);
    scan_kernel<<<1, 1024, 0, stream>>>(deg, rowptr, N_NODES);
    scatter_kernel<<<(N_EDGES + 255) / 256, 256, 0, stream>>>(src, dst, rowptr, cursor, esrc, N_EDGES);
    setup_misc<<<(256 * 512 + 512 * 128 + N_GRAPHS + 1 + 255) / 256, 256, 0, stream>>>(
        W1, W2, w1t, w2t, gid, gstart);

    // ===== layer 1: H=8, D=64; GEMM reads f32 x directly =====
    dim3 g1((N_NODES + 127) / 128, 512 / 128);
    gemm_mfma<128, 128, 64, 64, 8, 64, true><<<g1, 256, 0, stream>>>(
        x, w1t, feat1h, al1, ar1, el1, er1, N_NODES, 512, 256);
    node_aggr_wave<512, 8, true><<<(N_NODES * 64 + 255) / 256, 256, 0, stream>>>(
        feat1h, el1, er1, rowptr, esrc, b1, rst1h, N_NODES);

    // ===== layer 2: H=1, D=128; WN==D -> plain el/er stores =====
    dim3 g2((N_NODES + 63) / 64, 128 / 128);
    gemm_mfma<64, 128, 16, 128, 1, 128, false><<<g2, 256, 0, stream>>>(
        rst1h, w2t, feat2h, al2, ar2, el2, er2, N_NODES, 128, 512);
    node_aggr_wave<128, 1, false><<<(N_NODES * 16 + 255) / 256, 256, 0, stream>>>(
        feat2h, el2, er2, rowptr, esrc, b2, rst2, N_NODES);

    // ===== readout: per-graph mean (segmented, no atomics) =====
    seg_pool_kernel<<<N_GRAPHS, 1024, 0, stream>>>(rst2, gstart, out, 128);
}